// Round 6
// baseline (204.756 us; speedup 1.0000x reference)
//
#include <hip/hip_runtime.h>
#include <hip/hip_bf16.h>
#include <math.h>

// Problem constants (fixed by the reference setup_inputs()).
#define B_SZ    16384
#define NNZ     32
#define FT_OUT  1024
#define FEAT    768
#define BUCKETS 8
#define M_TOT   (2 * B_SZ)        // stm rows then nstm rows

typedef __bf16 bf16x8 __attribute__((ext_vector_type(8)));
typedef float  f32x4  __attribute__((ext_vector_type(4)));
typedef __attribute__((ext_vector_type(8))) short short8;

__device__ __forceinline__ unsigned short f2b(float f) {
    return __bfloat16_as_ushort(__float2bfloat16(f));
}
__device__ __forceinline__ float b2f(unsigned short u) {
    union { unsigned int i; float f; } x; x.i = ((unsigned int)u) << 16; return x.f;
}
__device__ __forceinline__ void gld_lds16(const void* g, void* l) {
    __builtin_amdgcn_global_load_lds(
        (const __attribute__((address_space(1))) unsigned int*)g,
        (__attribute__((address_space(3))) unsigned int*)l, 16, 0, 0);
}

// ---------------------------------------------------------------------------
// Kernel A: scatter sparse features -> dense bf16 board matrix A [32768][768].
// Rows 0..16383 = stm boards, 16384..32767 = nstm. One wave per row; LDS fp32
// row accumulator with atomicAdd (duplicate (b,f) pairs must SUM, like
// sparse_coo.to_dense()).
// ---------------------------------------------------------------------------
__global__ __launch_bounds__(256) void build_boards(
    const int*   __restrict__ stm_idx, const int* __restrict__ nstm_idx,
    const float* __restrict__ values,  unsigned short* __restrict__ A) {
    __shared__ float rowbuf[4][FEAT];
    const int wave = threadIdx.x >> 6, lane = threadIdx.x & 63;
    const int m = blockIdx.x * 4 + wave;
    const int board = m & (B_SZ - 1);
    const int* idx = (m >= B_SZ) ? nstm_idx : stm_idx;
    float* rb = rowbuf[wave];
#pragma unroll
    for (int i = 0; i < FEAT / 64; ++i) rb[i * 64 + lane] = 0.0f;
    __syncthreads();
    if (lane < NNZ) {
        int   f = idx[(board * NNZ + lane) * 2 + 1];
        float v = values[board * NNZ + lane];
        atomicAdd(&rb[f], v);
    }
    __syncthreads();
    unsigned int* dst = (unsigned int*)(A + (long)m * FEAT);
#pragma unroll
    for (int i = 0; i < FEAT / 128; ++i) {
        int e = i * 64 + lane;
        unsigned int lo = f2b(rb[2 * e]), hi = f2b(rb[2 * e + 1]);
        dst[e] = lo | (hi << 16);
    }
}

// ---------------------------------------------------------------------------
// Kernel B: cast ft_w [FT_OUT][FEAT] fp32 -> bf16 (already B^T layout [N][K]).
// ---------------------------------------------------------------------------
__global__ __launch_bounds__(256) void cvt_ftw(const float2* __restrict__ src,
                                               unsigned int* __restrict__ dst) {
    int i = blockIdx.x * 256 + threadIdx.x;   // over FT_OUT*FEAT/2
    float2 v = src[i];
    dst[i] = (unsigned int)f2b(v.x) | ((unsigned int)f2b(v.y) << 16);
}

// ---------------------------------------------------------------------------
// Kernel C: bf16 MFMA GEMM  C[m][n] = sum_k A[m][k]*W[n][k]  (m97 structure:
// 128x128 tile, BK=64, 4 waves 2x2, global_load_lds w16, 2-barrier K-loop,
// 16x16x32 MFMA) with fused head epilogue:
//   h = clip(acc + ft_b[n], 0, 1);  atomicAdd(logit[board], h*out_w[bkt][..]).
// ---------------------------------------------------------------------------
#define BM 128
#define BN 128
#define BK 64

__global__ __launch_bounds__(256) void gemm_head(
    const unsigned short* __restrict__ A,   // [M_TOT][FEAT] bf16
    const unsigned short* __restrict__ W,   // [FT_OUT][FEAT] bf16
    const float* __restrict__ ft_b,         // [FT_OUT]
    const float* __restrict__ out_w,        // [BUCKETS][2*FT_OUT]
    const int*   __restrict__ buckets,      // [B_SZ]
    float*       __restrict__ logit)        // [B_SZ], pre-zeroed
{
    __shared__ unsigned short smA[BM * BK];  // [128 rows][64 k] linear
    __shared__ unsigned short smB[BN * BK];
    const int wave = threadIdx.x >> 6, lane = threadIdx.x & 63;
    const int wm = wave >> 1, wn = wave & 1;            // 2x2 wave grid
    const int tileM = blockIdx.x * BM;                  // 0..32640
    const int tileN = blockIdx.y * BN;                  // 0..896

    f32x4 acc[4][4] = {};

    const int srow = wave * 32 + (lane >> 3);           // staging row base (q adds 8)
    const int skoff = (lane & 7) * 8;                   // staging k offset (elems)

    for (int kt = 0; kt < FEAT / BK; ++kt) {
        const int k0 = kt * BK;
        __syncthreads();                                // buffer free
#pragma unroll
        for (int q = 0; q < 4; ++q) {
            int r = srow + q * 8;                       // 0..127 across waves
            gld_lds16(A + (long)(tileM + r) * FEAT + k0 + skoff, smA + (wave * 32 + q * 8) * BK);
            gld_lds16(W + (long)(tileN + r) * FEAT + k0 + skoff, smB + (wave * 32 + q * 8) * BK);
        }
        __syncthreads();                                // loads drained (vmcnt0 at barrier)
#pragma unroll
        for (int ki = 0; ki < 2; ++ki) {
            bf16x8 af[4], bfr[4];
#pragma unroll
            for (int f = 0; f < 4; ++f) {
                af[f]  = *(const bf16x8*)(smA + (wm * 64 + f * 16 + (lane & 15)) * BK + ki * 32 + (lane >> 4) * 8);
                bfr[f] = *(const bf16x8*)(smB + (wn * 64 + f * 16 + (lane & 15)) * BK + ki * 32 + (lane >> 4) * 8);
            }
#pragma unroll
            for (int mf = 0; mf < 4; ++mf)
#pragma unroll
                for (int nf = 0; nf < 4; ++nf)
                    acc[mf][nf] = __builtin_amdgcn_mfma_f32_16x16x32_bf16(
                        af[mf], bfr[nf], acc[mf][nf], 0, 0, 0);
        }
    }

    // ---- fused head epilogue ----
    // C/D layout (verified m89/m91): col = lane&15, row = (lane>>4)*4 + reg.
    float ftb[4]; int cols[4];
#pragma unroll
    for (int nf = 0; nf < 4; ++nf) {
        cols[nf] = tileN + wn * 64 + nf * 16 + (lane & 15);
        ftb[nf]  = ft_b[cols[nf]];
    }
    const int sideoff = (tileM >= B_SZ) ? FT_OUT : 0;   // nstm half of out_w row

#pragma unroll
    for (int mf = 0; mf < 4; ++mf) {
#pragma unroll
        for (int r = 0; r < 4; ++r) {
            int mloc  = wm * 64 + mf * 16 + (lane >> 4) * 4 + r;
            int board = (tileM + mloc) & (B_SZ - 1);
            int bkt   = buckets[board];
            const float* ow = out_w + bkt * (2 * FT_OUT) + sideoff;
            float p = 0.0f;
#pragma unroll
            for (int nf = 0; nf < 4; ++nf) {
                float h = acc[mf][nf][r] + ftb[nf];
                h = fminf(fmaxf(h, 0.0f), 1.0f);
                p += h * ow[cols[nf]];
            }
            p += __shfl_xor(p, 1);
            p += __shfl_xor(p, 2);
            p += __shfl_xor(p, 4);
            p += __shfl_xor(p, 8);
            if ((lane & 15) == 0) atomicAdd(logit + board, p);
        }
    }
}

// ---------------------------------------------------------------------------
// Kernel D: out[b] = sigmoid(logit[b] + out_b[bucket[b]]).
// ---------------------------------------------------------------------------
__global__ __launch_bounds__(256) void finish(const float* __restrict__ logit,
                                              const int* __restrict__ buckets,
                                              const float* __restrict__ out_b,
                                              float* __restrict__ out) {
    int b = blockIdx.x * 256 + threadIdx.x;
    float l = logit[b] + out_b[buckets[b]];
    out[b] = 1.0f / (1.0f + expf(-l));
}

// ===========================================================================
// Fallback (R2 gather path) if ws_size is too small for the dense A matrix.
// ===========================================================================
__global__ __launch_bounds__(256) void transpose_ftw_bf16(
    const float* __restrict__ ft_w, unsigned short* __restrict__ ftT) {
    __shared__ float tile[32][33];
    const int fo = blockIdx.x * 32, oo = blockIdx.y * 32;
    const int tx = threadIdx.x & 31, ty = threadIdx.x >> 5;
#pragma unroll
    for (int i = 0; i < 4; ++i)
        tile[ty + 8 * i][tx] = ft_w[(oo + ty + 8 * i) * FEAT + fo + tx];
    __syncthreads();
#pragma unroll
    for (int i = 0; i < 4; ++i)
        ftT[(fo + ty + 8 * i) * FT_OUT + oo + tx] = f2b(tile[tx][ty + 8 * i]);
}

__global__ __launch_bounds__(256) void nn_fwd(
    const int* __restrict__ stm_idx, const int* __restrict__ nstm_idx,
    const float* __restrict__ values, const int* __restrict__ buckets,
    const unsigned short* __restrict__ ftT, const float* __restrict__ ft_b,
    const float* __restrict__ out_w, const float* __restrict__ out_b,
    float* __restrict__ out) {
    const int wave = threadIdx.x >> 6, lane = threadIdx.x & 63;
    const int b = __builtin_amdgcn_readfirstlane(blockIdx.x * 4 + wave);
    float acc_s[2][8], acc_n[2][8];
#pragma unroll
    for (int c = 0; c < 2; ++c) {
        const float4* fb = (const float4*)(ft_b + c * 512 + lane * 8);
        float4 b0 = fb[0], b1 = fb[1];
        float t[8] = {b0.x,b0.y,b0.z,b0.w,b1.x,b1.y,b1.z,b1.w};
#pragma unroll
        for (int j = 0; j < 8; ++j) { acc_s[c][j] = t[j]; acc_n[c][j] = t[j]; }
    }
    const int base = b * NNZ;
#pragma unroll 4
    for (int k = 0; k < NNZ; ++k) {
        const int fs = stm_idx[(base + k) * 2 + 1];
        const int fn = nstm_idx[(base + k) * 2 + 1];
        const float v = values[base + k];
        const unsigned short* cs = ftT + fs * FT_OUT;
        const unsigned short* cn = ftT + fn * FT_OUT;
#pragma unroll
        for (int c = 0; c < 2; ++c) {
            short8 ws = *(const short8*)(cs + c * 512 + lane * 8);
            short8 wn2 = *(const short8*)(cn + c * 512 + lane * 8);
#pragma unroll
            for (int j = 0; j < 8; ++j) {
                acc_s[c][j] = fmaf(v, b2f((unsigned short)ws[j]), acc_s[c][j]);
                acc_n[c][j] = fmaf(v, b2f((unsigned short)wn2[j]), acc_n[c][j]);
            }
        }
    }
    const int bkt = __builtin_amdgcn_readfirstlane(buckets[b]);
    const float* ow = out_w + bkt * (2 * FT_OUT);
    float part = 0.0f;
#pragma unroll
    for (int c = 0; c < 2; ++c) {
        const float4* ps = (const float4*)(ow + c * 512 + lane * 8);
        const float4* pn = (const float4*)(ow + FT_OUT + c * 512 + lane * 8);
        float4 s0 = ps[0], s1 = ps[1], n0 = pn[0], n1 = pn[1];
        float sw[8] = {s0.x,s0.y,s0.z,s0.w,s1.x,s1.y,s1.z,s1.w};
        float nw[8] = {n0.x,n0.y,n0.z,n0.w,n1.x,n1.y,n1.z,n1.w};
#pragma unroll
        for (int j = 0; j < 8; ++j) {
            part += fminf(fmaxf(acc_s[c][j], 0.f), 1.f) * sw[j];
            part += fminf(fmaxf(acc_n[c][j], 0.f), 1.f) * nw[j];
        }
    }
#pragma unroll
    for (int off = 32; off >= 1; off >>= 1) part += __shfl_xor(part, off);
    if (lane == 0) out[b] = 1.0f / (1.0f + expf(-(part + out_b[bkt])));
}

// ---------------------------------------------------------------------------
// setup_inputs() order:
//   0 stm_indices  1 nstm_indices  2 values  3 buckets  4 size
//   5 ft_w [1024,768] f32  6 ft_b [1024]  7 out_w [8,2048]  8 out_b [8]
// ---------------------------------------------------------------------------
extern "C" void kernel_launch(void* const* d_in, const int* in_sizes, int n_in,
                              void* d_out, int out_size, void* d_ws, size_t ws_size,
                              hipStream_t stream) {
    const int*   stm_idx  = (const int*)  d_in[0];
    const int*   nstm_idx = (const int*)  d_in[1];
    const float* values   = (const float*)d_in[2];
    const int*   buckets  = (const int*)  d_in[3];
    const float* ft_w     = (const float*)d_in[5];
    const float* ft_b     = (const float*)d_in[6];
    const float* out_w    = (const float*)d_in[7];
    const float* out_b    = (const float*)d_in[8];
    float*       out      = (float*)d_out;

    const size_t szA = (size_t)M_TOT * FEAT * 2;        // 50.3 MB dense boards
    const size_t szW = (size_t)FT_OUT * FEAT * 2;       // 1.5 MB bf16 weights
    const size_t NEED = szA + szW + (size_t)B_SZ * 4;

    if (ws_size >= NEED) {
        unsigned short* A  = (unsigned short*)d_ws;
        unsigned short* W  = (unsigned short*)((char*)d_ws + szA);
        float*          lg = (float*)((char*)d_ws + szA + szW);

        cvt_ftw<<<(FT_OUT * FEAT / 2) / 256, 256, 0, stream>>>(
            (const float2*)ft_w, (unsigned int*)W);
        build_boards<<<M_TOT / 4, 256, 0, stream>>>(stm_idx, nstm_idx, values, A);
        hipMemsetAsync(lg, 0, (size_t)B_SZ * 4, stream);
        gemm_head<<<dim3(M_TOT / BM, FT_OUT / BN), 256, 0, stream>>>(
            A, W, ft_b, out_w, buckets, lg);
        finish<<<B_SZ / 256, 256, 0, stream>>>(lg, buckets, out_b, out);
    } else {
        unsigned short* ftT = (unsigned short*)d_ws;    // 1.5 MB
        transpose_ftw_bf16<<<dim3(FEAT / 32, FT_OUT / 32), 256, 0, stream>>>(ft_w, ftT);
        nn_fwd<<<B_SZ / 4, 256, 0, stream>>>(stm_idx, nstm_idx, values, buckets,
                                             ftT, ft_b, out_w, out_b, out);
    }
}

// Round 7
// 178.791 us; speedup vs baseline: 1.1452x; 1.1452x over previous
//
#include <hip/hip_runtime.h>
#include <hip/hip_bf16.h>
#include <math.h>

// Problem constants (fixed by the reference setup_inputs()).
#define B_SZ    16384
#define NNZ     32
#define FT_OUT  1024
#define FEAT    768
#define BUCKETS 8
#define M_TOT   (2 * B_SZ)        // stm rows then nstm rows

typedef __bf16 bf16x8 __attribute__((ext_vector_type(8)));
typedef float  f32x4  __attribute__((ext_vector_type(4)));
typedef __attribute__((ext_vector_type(8))) short short8;

__device__ __forceinline__ unsigned short f2b(float f) {
    return __bfloat16_as_ushort(__float2bfloat16(f));
}
__device__ __forceinline__ float b2f(unsigned short u) {
    union { unsigned int i; float f; } x; x.i = ((unsigned int)u) << 16; return x.f;
}
__device__ __forceinline__ void gld_lds16(const void* g, void* l) {
    __builtin_amdgcn_global_load_lds(
        (const __attribute__((address_space(1))) unsigned int*)g,
        (__attribute__((address_space(3))) unsigned int*)l, 16, 0, 0);
}

// ---------------------------------------------------------------------------
// Kernel A: scatter sparse features -> dense bf16 board matrix A [32768][768].
// ---------------------------------------------------------------------------
__global__ __launch_bounds__(256) void build_boards(
    const int*   __restrict__ stm_idx, const int* __restrict__ nstm_idx,
    const float* __restrict__ values,  unsigned short* __restrict__ A) {
    __shared__ float rowbuf[4][FEAT];
    const int wave = threadIdx.x >> 6, lane = threadIdx.x & 63;
    const int m = blockIdx.x * 4 + wave;
    const int board = m & (B_SZ - 1);
    const int* idx = (m >= B_SZ) ? nstm_idx : stm_idx;
    float* rb = rowbuf[wave];
#pragma unroll
    for (int i = 0; i < FEAT / 64; ++i) rb[i * 64 + lane] = 0.0f;
    __syncthreads();
    if (lane < NNZ) {
        int   f = idx[(board * NNZ + lane) * 2 + 1];
        float v = values[board * NNZ + lane];
        atomicAdd(&rb[f], v);
    }
    __syncthreads();
    unsigned int* dst = (unsigned int*)(A + (long)m * FEAT);
#pragma unroll
    for (int i = 0; i < FEAT / 128; ++i) {
        int e = i * 64 + lane;
        unsigned int lo = f2b(rb[2 * e]), hi = f2b(rb[2 * e + 1]);
        dst[e] = lo | (hi << 16);
    }
}

// ---------------------------------------------------------------------------
// Kernel B: cast ft_w [FT_OUT][FEAT] fp32 -> bf16 (already B^T layout [N][K]).
// ---------------------------------------------------------------------------
__global__ __launch_bounds__(256) void cvt_ftw(const float2* __restrict__ src,
                                               unsigned int* __restrict__ dst) {
    int i = blockIdx.x * 256 + threadIdx.x;   // over FT_OUT*FEAT/2
    float2 v = src[i];
    dst[i] = (unsigned int)f2b(v.x) | ((unsigned int)f2b(v.y) << 16);
}

// ---------------------------------------------------------------------------
// Kernel C: bf16 MFMA GEMM with fused head epilogue. R7 changes vs R6:
//  - T2 both-sides XOR swizzle: LDS dest stays linear (global_load_lds
//    constraint, m104); SOURCE k-chunk = (lane&7)^(lane>>3); ds_read chunk
//    = (ki*4 + (lane>>4)) ^ (lane&7).  16-way bank conflict -> 0.
//  - double-buffered prefetch: stage(t+1) issued BEFORE compute(t), single
//    __syncthreads per K-step (vmcnt(0) there lands after MFMA phase).
//  - T1 XCD chunk swizzle (2048 blocks % 8 == 0 -> simple form bijective),
//    N-index fastest so the 8 blocks sharing an A-tile run on one XCD.
// ---------------------------------------------------------------------------
#define BM 128
#define BN 128
#define BK 64
#define NKT (FEAT / BK)           // 12 K-steps

__global__ __launch_bounds__(256, 2) void gemm_head(
    const unsigned short* __restrict__ A,   // [M_TOT][FEAT] bf16
    const unsigned short* __restrict__ W,   // [FT_OUT][FEAT] bf16
    const float* __restrict__ ft_b,         // [FT_OUT]
    const float* __restrict__ out_w,        // [BUCKETS][2*FT_OUT]
    const int*   __restrict__ buckets,      // [B_SZ]
    float*       __restrict__ logit)        // [B_SZ], pre-zeroed
{
    __shared__ unsigned short smA[2][BM * BK];   // 2 x 16 KB
    __shared__ unsigned short smB[2][BN * BK];   // 2 x 16 KB
    const int wave = threadIdx.x >> 6, lane = threadIdx.x & 63;
    const int wm = wave >> 1, wn = wave & 1;            // 2x2 wave grid

    // T1: xcd = bid&7 owns 256 contiguous wg ids; within, n fastest.
    const int bid = blockIdx.x;                          // 0..2047
    const int wg  = (bid & 7) * 256 + (bid >> 3);
    const int tileM = (wg >> 3) * BM;                    // 256 M-tiles
    const int tileN = (wg & 7) * BN;                     // 8 N-tiles

    f32x4 acc[4][4] = {};

    const int srow  = wave * 32 + (lane >> 3);           // staging row (q adds 8)
    // T2 source-side: physical chunk c holds logical chunk c ^ (row&7);
    // row&7 == lane>>3 for all q (wave*32, q*8 are 0 mod 8).
    const int skoff = ((lane & 7) ^ (lane >> 3)) * 8;    // elems

    // ---- prologue: stage kt=0 into buf0, drain ----
#pragma unroll
    for (int q = 0; q < 4; ++q) {
        gld_lds16(A + (long)(tileM + srow + q * 8) * FEAT + skoff,
                  &smA[0][(wave * 32 + q * 8) * BK]);
        gld_lds16(W + (long)(tileN + srow + q * 8) * FEAT + skoff,
                  &smB[0][(wave * 32 + q * 8) * BK]);
    }
    __syncthreads();

    const int cx = lane & 7;                             // read-side xor key
    const int rq = lane >> 4;                            // k-quarter 0..3

    for (int kt = 0; kt < NKT; ++kt) {
        const int cur = kt & 1;
        // ---- issue next tile's loads into the other buffer (prefetch) ----
        if (kt + 1 < NKT) {
            const int nk0 = (kt + 1) * BK;
#pragma unroll
            for (int q = 0; q < 4; ++q) {
                gld_lds16(A + (long)(tileM + srow + q * 8) * FEAT + nk0 + skoff,
                          &smA[cur ^ 1][(wave * 32 + q * 8) * BK]);
                gld_lds16(W + (long)(tileN + srow + q * 8) * FEAT + nk0 + skoff,
                          &smB[cur ^ 1][(wave * 32 + q * 8) * BK]);
            }
        }
        // ---- compute from current buffer ----
#pragma unroll
        for (int ki = 0; ki < 2; ++ki) {
            bf16x8 af[4], bfr[4];
#pragma unroll
            for (int f = 0; f < 4; ++f) {
                const int rowA = wm * 64 + f * 16 + (lane & 15);
                const int rowB = wn * 64 + f * 16 + (lane & 15);
                const int koff = (((ki * 4 + rq) ^ cx) * 8);   // swizzled chunk
                af[f]  = *(const bf16x8*)(&smA[cur][rowA * BK + koff]);
                bfr[f] = *(const bf16x8*)(&smB[cur][rowB * BK + koff]);
            }
#pragma unroll
            for (int mf = 0; mf < 4; ++mf)
#pragma unroll
                for (int nf = 0; nf < 4; ++nf)
                    acc[mf][nf] = __builtin_amdgcn_mfma_f32_16x16x32_bf16(
                        af[mf], bfr[nf], acc[mf][nf], 0, 0, 0);
        }
        // ---- one barrier per K-step: drains prefetch (vmcnt0) + protects
        //      buf[cur] from being restaged before all waves finished it ----
        __syncthreads();
    }

    // ---- fused head epilogue ----
    // C/D layout (verified m89/m91): col = lane&15, row = (lane>>4)*4 + reg.
    float ftb[4]; int cols[4];
#pragma unroll
    for (int nf = 0; nf < 4; ++nf) {
        cols[nf] = tileN + wn * 64 + nf * 16 + (lane & 15);
        ftb[nf]  = ft_b[cols[nf]];
    }
    const int sideoff = (tileM >= B_SZ) ? FT_OUT : 0;   // nstm half of out_w row

#pragma unroll
    for (int mf = 0; mf < 4; ++mf) {
#pragma unroll
        for (int r = 0; r < 4; ++r) {
            int mloc  = wm * 64 + mf * 16 + (lane >> 4) * 4 + r;
            int board = (tileM + mloc) & (B_SZ - 1);
            int bkt   = buckets[board];
            const float* ow = out_w + bkt * (2 * FT_OUT) + sideoff;
            float p = 0.0f;
#pragma unroll
            for (int nf = 0; nf < 4; ++nf) {
                float h = acc[mf][nf][r] + ftb[nf];
                h = fminf(fmaxf(h, 0.0f), 1.0f);
                p += h * ow[cols[nf]];
            }
            p += __shfl_xor(p, 1);
            p += __shfl_xor(p, 2);
            p += __shfl_xor(p, 4);
            p += __shfl_xor(p, 8);
            if ((lane & 15) == 0) atomicAdd(logit + board, p);
        }
    }
}

// ---------------------------------------------------------------------------
// Kernel D: out[b] = sigmoid(logit[b] + out_b[bucket[b]]).
// ---------------------------------------------------------------------------
__global__ __launch_bounds__(256) void finish(const float* __restrict__ logit,
                                              const int* __restrict__ buckets,
                                              const float* __restrict__ out_b,
                                              float* __restrict__ out) {
    int b = blockIdx.x * 256 + threadIdx.x;
    float l = logit[b] + out_b[buckets[b]];
    out[b] = 1.0f / (1.0f + expf(-l));
}

// ===========================================================================
// Fallback (R2 gather path) if ws_size is too small for the dense A matrix.
// ===========================================================================
__global__ __launch_bounds__(256) void transpose_ftw_bf16(
    const float* __restrict__ ft_w, unsigned short* __restrict__ ftT) {
    __shared__ float tile[32][33];
    const int fo = blockIdx.x * 32, oo = blockIdx.y * 32;
    const int tx = threadIdx.x & 31, ty = threadIdx.x >> 5;
#pragma unroll
    for (int i = 0; i < 4; ++i)
        tile[ty + 8 * i][tx] = ft_w[(oo + ty + 8 * i) * FEAT + fo + tx];
    __syncthreads();
#pragma unroll
    for (int i = 0; i < 4; ++i)
        ftT[(fo + ty + 8 * i) * FT_OUT + oo + tx] = f2b(tile[tx][ty + 8 * i]);
}

__global__ __launch_bounds__(256) void nn_fwd(
    const int* __restrict__ stm_idx, const int* __restrict__ nstm_idx,
    const float* __restrict__ values, const int* __restrict__ buckets,
    const unsigned short* __restrict__ ftT, const float* __restrict__ ft_b,
    const float* __restrict__ out_w, const float* __restrict__ out_b,
    float* __restrict__ out) {
    const int wave = threadIdx.x >> 6, lane = threadIdx.x & 63;
    const int b = __builtin_amdgcn_readfirstlane(blockIdx.x * 4 + wave);
    float acc_s[2][8], acc_n[2][8];
#pragma unroll
    for (int c = 0; c < 2; ++c) {
        const float4* fb = (const float4*)(ft_b + c * 512 + lane * 8);
        float4 b0 = fb[0], b1 = fb[1];
        float t[8] = {b0.x,b0.y,b0.z,b0.w,b1.x,b1.y,b1.z,b1.w};
#pragma unroll
        for (int j = 0; j < 8; ++j) { acc_s[c][j] = t[j]; acc_n[c][j] = t[j]; }
    }
    const int base = b * NNZ;
#pragma unroll 4
    for (int k = 0; k < NNZ; ++k) {
        const int fs = stm_idx[(base + k) * 2 + 1];
        const int fn = nstm_idx[(base + k) * 2 + 1];
        const float v = values[base + k];
        const unsigned short* cs = ftT + fs * FT_OUT;
        const unsigned short* cn = ftT + fn * FT_OUT;
#pragma unroll
        for (int c = 0; c < 2; ++c) {
            short8 ws = *(const short8*)(cs + c * 512 + lane * 8);
            short8 wn2 = *(const short8*)(cn + c * 512 + lane * 8);
#pragma unroll
            for (int j = 0; j < 8; ++j) {
                acc_s[c][j] = fmaf(v, b2f((unsigned short)ws[j]), acc_s[c][j]);
                acc_n[c][j] = fmaf(v, b2f((unsigned short)wn2[j]), acc_n[c][j]);
            }
        }
    }
    const int bkt = __builtin_amdgcn_readfirstlane(buckets[b]);
    const float* ow = out_w + bkt * (2 * FT_OUT);
    float part = 0.0f;
#pragma unroll
    for (int c = 0; c < 2; ++c) {
        const float4* ps = (const float4*)(ow + c * 512 + lane * 8);
        const float4* pn = (const float4*)(ow + FT_OUT + c * 512 + lane * 8);
        float4 s0 = ps[0], s1 = ps[1], n0 = pn[0], n1 = pn[1];
        float sw[8] = {s0.x,s0.y,s0.z,s0.w,s1.x,s1.y,s1.z,s1.w};
        float nw[8] = {n0.x,n0.y,n0.z,n0.w,n1.x,n1.y,n1.z,n1.w};
#pragma unroll
        for (int j = 0; j < 8; ++j) {
            part += fminf(fmaxf(acc_s[c][j], 0.f), 1.f) * sw[j];
            part += fminf(fmaxf(acc_n[c][j], 0.f), 1.f) * nw[j];
        }
    }
#pragma unroll
    for (int off = 32; off >= 1; off >>= 1) part += __shfl_xor(part, off);
    if (lane == 0) out[b] = 1.0f / (1.0f + expf(-(part + out_b[bkt])));
}

// ---------------------------------------------------------------------------
// setup_inputs() order:
//   0 stm_indices  1 nstm_indices  2 values  3 buckets  4 size
//   5 ft_w [1024,768] f32  6 ft_b [1024]  7 out_w [8,2048]  8 out_b [8]
// ---------------------------------------------------------------------------
extern "C" void kernel_launch(void* const* d_in, const int* in_sizes, int n_in,
                              void* d_out, int out_size, void* d_ws, size_t ws_size,
                              hipStream_t stream) {
    const int*   stm_idx  = (const int*)  d_in[0];
    const int*   nstm_idx = (const int*)  d_in[1];
    const float* values   = (const float*)d_in[2];
    const int*   buckets  = (const int*)  d_in[3];
    const float* ft_w     = (const float*)d_in[5];
    const float* ft_b     = (const float*)d_in[6];
    const float* out_w    = (const float*)d_in[7];
    const float* out_b    = (const float*)d_in[8];
    float*       out      = (float*)d_out;

    const size_t szA = (size_t)M_TOT * FEAT * 2;        // 50.3 MB dense boards
    const size_t szW = (size_t)FT_OUT * FEAT * 2;       // 1.5 MB bf16 weights
    const size_t NEED = szA + szW + (size_t)B_SZ * 4;

    if (ws_size >= NEED) {
        unsigned short* A  = (unsigned short*)d_ws;
        unsigned short* W  = (unsigned short*)((char*)d_ws + szA);
        float*          lg = (float*)((char*)d_ws + szA + szW);

        cvt_ftw<<<(FT_OUT * FEAT / 2) / 256, 256, 0, stream>>>(
            (const float2*)ft_w, (unsigned int*)W);
        build_boards<<<M_TOT / 4, 256, 0, stream>>>(stm_idx, nstm_idx, values, A);
        hipMemsetAsync(lg, 0, (size_t)B_SZ * 4, stream);
        gemm_head<<<(M_TOT / BM) * (FT_OUT / BN), 256, 0, stream>>>(
            A, W, ft_b, out_w, buckets, lg);
        finish<<<B_SZ / 256, 256, 0, stream>>>(lg, buckets, out_b, out);
    } else {
        unsigned short* ftT = (unsigned short*)d_ws;    // 1.5 MB
        transpose_ftw_bf16<<<dim3(FEAT / 32, FT_OUT / 32), 256, 0, stream>>>(ft_w, ftT);
        nn_fwd<<<B_SZ / 4, 256, 0, stream>>>(stm_idx, nstm_idx, values, buckets,
                                             ftT, ft_b, out_w, out_b, out);
    }
}